// Round 8
// baseline (209.705 us; speedup 1.0000x reference)
//
#include <hip/hip_runtime.h>
#include <hip/hip_bf16.h>

#define DEV __device__ __forceinline__

typedef __attribute__((ext_vector_type(8)))  __bf16    bf16x8;
typedef __attribute__((ext_vector_type(4)))  int       int4v;
typedef __attribute__((ext_vector_type(2)))  unsigned  uint2v;
typedef __attribute__((ext_vector_type(16))) float     vfloat16;

#if __has_builtin(__builtin_amdgcn_permlane32_swap)
#define HAVE_PLSWAP 1
#endif

// pack two fp32 -> one dword of two bf16 (round-nearest-ties-up): 2 adds + 1 perm
DEV int pkbf(float a, float b) {
    unsigned ua = __builtin_bit_cast(unsigned, a) + 0x8000u;
    unsigned ub = __builtin_bit_cast(unsigned, b) + 0x8000u;
    return (int)__builtin_amdgcn_perm(ua, ub, 0x03020706u);
}

DEV bf16x8 i4_to_frag(int4v v) { return __builtin_bit_cast(bf16x8, v); }

DEV vfloat16 mfma32(bf16x8 a, bf16x8 b, vfloat16 c) {
    return __builtin_amdgcn_mfma_f32_32x32x16_bf16(a, b, c, 0, 0, 0);
}

DEV vfloat16 zc() {
    vfloat16 z;
#pragma unroll
    for (int i = 0; i < 16; ++i) z[i] = 0.f;
    return z;
}

// ---- C-layout 8-reg group -> B-frag (K=16), relu folded ----
// C layout: col=lane&31, row=(reg&3)+8*(reg>>2)+4*h   (h = lane>=32)
// B layout: n=lane&31,  k=(lane>>5)*8+j
DEV bf16x8 xposeB(float c0, float c1, float c2, float c3,
                  float c4, float c5, float c6, float c7, bool h) {
    int R0 = pkbf(fmaxf(c0, 0.f), fmaxf(c1, 0.f));
    int R1 = pkbf(fmaxf(c2, 0.f), fmaxf(c3, 0.f));
    int R2 = pkbf(fmaxf(c4, 0.f), fmaxf(c5, 0.f));
    int R3 = pkbf(fmaxf(c6, 0.f), fmaxf(c7, 0.f));
#ifdef HAVE_PLSWAP
    uint2v p0 = __builtin_amdgcn_permlane32_swap((unsigned)R0, (unsigned)R2, false, false);
    uint2v p1 = __builtin_amdgcn_permlane32_swap((unsigned)R1, (unsigned)R3, false, false);
    int4v v;
    v.x = (int)p0.x; v.y = (int)p1.x; v.z = (int)p0.y; v.w = (int)p1.y;
#else
    int S0 = h ? R0 : R2;
    int S1 = h ? R1 : R3;
    int Y0 = __shfl_xor(S0, 32, 64);
    int Y1 = __shfl_xor(S1, 32, 64);
    int4v v;
    v.x = h ? Y0 : R0;
    v.y = h ? Y1 : R1;
    v.z = h ? R2 : Y0;
    v.w = h ? R3 : Y1;
#endif
    return i4_to_frag(v);
}

// A-frag: A[m][k_global], m=lane&31, k_global = koff + 8*h + j.
// W row-major (K, ld).  bias!=null -> k_global==K slot carries bias[m].
DEV bf16x8 make_afrag(const float* __restrict__ W, const float* __restrict__ bias,
                      int ld, int Mact, int K, int koff, int lane) {
    int m = lane & 31;
    int h = lane >> 5;
    int d[4];
#pragma unroll
    for (int i = 0; i < 4; ++i) {
        int k0 = koff + h * 8 + 2 * i;
        int k1 = k0 + 1;
        float w0 = 0.f, w1 = 0.f;
        if (m < Mact) {
            if (k0 < K) w0 = W[k0 * ld + m];
            else if (bias && k0 == K) w0 = bias[m];
            if (k1 < K) w1 = W[k1 * ld + m];
            else if (bias && k1 == K) w1 = bias[m];
        }
        d[i] = pkbf(w0, w1);
    }
    int4v v; v.x = d[0]; v.y = d[1]; v.z = d[2]; v.w = d[3];
    return i4_to_frag(v);
}

// bias vector in C layout (all 32 rows)
DEV vfloat16 bvec32(const float* __restrict__ b, int lane) {
    int h = lane >> 5;
    vfloat16 v;
#pragma unroll
    for (int reg = 0; reg < 16; ++reg)
        v[reg] = b[(reg & 3) + 8 * (reg >> 2) + 4 * h];
    return v;
}

// B1 frag from pre-packed dwords: x at k=0..3, 1.0 at k=4 (bias slot).
// h-lanes hit A1 columns k>=8 which are zero -> no masking needed.
DEV bf16x8 b1_from(int2 d) {
    int4v v;
    v.x = d.x;
    v.y = d.y;
    v.z = 0x00003f80;          // bf16(1.0) at k=4
    v.w = 0;
    return i4_to_frag(v);
}

// LDS x-stage: pre-packed bf16, [agent][row] int2, agent stride 66 dwords
#define XSTRIDE 66
#define TILES_PER_BLK 2

__global__ __launch_bounds__(256)
__attribute__((amdgpu_waves_per_eu(4, 4)))   // 128-VGPR budget; single-chain
// live set ~110 regs fits -> MFMA accums stay in arch VGPRs (no acc shuttle)
void dqn_kernel(const float* __restrict__ x, const int* __restrict__ selp,
                const float* __restrict__ oW1, const float* __restrict__ ob1,
                const float* __restrict__ oW2, const float* __restrict__ ob2,
                const float* __restrict__ oW3, const float* __restrict__ ob3,
                const float* __restrict__ sW1, const float* __restrict__ sb1,
                const float* __restrict__ sW2, const float* __restrict__ sb2,
                const float* __restrict__ sW3, const float* __restrict__ sb3,
                const float* __restrict__ gW1, const float* __restrict__ gb1,
                const float* __restrict__ gW2, const float* __restrict__ gb2,
                float* __restrict__ out)
{
    __shared__ int   lds_xb[2][32 * XSTRIDE]; // 2 x 8.4 KB double-buffered x
    __shared__ float lds_red[3][8][64];       // 6 KB partial agent-sums

    const int tid  = threadIdx.x;
    const int lane = tid & 63;
    const int wave = tid >> 6;
    const bool h = lane >= 32;
    const int c = lane & 31;
    const int sel = *selp;

    // ---- stage tile 0 (all 256 threads, coalesced) ----
    {
        int tile0 = blockIdx.x * TILES_PER_BLK;
        const float* xblk = x + (size_t)tile0 * 32 * 128;
#pragma unroll
        for (int k = 0; k < 4; ++k) {
            int f = tid + 256 * k;            // float4 cell in 32x32 tile
            int row = f >> 5;
            int ag  = f & 31;
            float4 v = *(const float4*)(xblk + (size_t)f * 4);
            int2 d;
            d.x = pkbf(v.x, v.y);
            d.y = pkbf(v.z, v.w);
            *(int2*)&lds_xb[0][ag * XSTRIDE + row * 2] = d;
        }
    }

    for (int t = 0; t < TILES_PER_BLK; ++t) {
        const int tile  = blockIdx.x * TILES_PER_BLK + t;
        const int base0 = tile * 32;
        const int buf   = t & 1;

        // per-tile "other"-MLP fragments (L2-warm after tile 0)
        bf16x8 A1   = make_afrag(oW1, ob1,     32, 32, 4,  0,  lane);
        bf16x8 A2lo = make_afrag(oW2, nullptr, 32, 32, 32, 0,  lane);
        bf16x8 A2hi = make_afrag(oW2, nullptr, 32, 32, 32, 16, lane);
        bf16x8 A3lo = make_afrag(oW3, nullptr, 16, 16, 32, 0,  lane);
        bf16x8 A3hi = make_afrag(oW3, nullptr, 16, 16, 32, 16, lane);
        vfloat16 b2 = bvec32(ob2, lane);
        float b3s[8];                          // L3 bias, folded into sum
#pragma unroll
        for (int j = 0; j < 8; ++j) b3s[j] = ob3[(j & 3) + 8 * (j >> 2) + (h ? 4 : 0)];

        __syncthreads();                       // buffer `buf` ready

        // ---- main loop: 8 agents, single chain (D != C, no accum copies) ----
        float sum[8] = {0.f, 0.f, 0.f, 0.f, 0.f, 0.f, 0.f, 0.f};
        const int a0 = wave * 8;
        const int* xb = &lds_xb[buf][a0 * XSTRIDE + c * 2];

#pragma unroll
        for (int i = 0; i < 8; ++i) {
            int2 da = *(const int2*)(xb + i * XSTRIDE);
            vfloat16 C1 = mfma32(A1, b1_from(da), zc());
            bf16x8 Blo = xposeB(C1[0], C1[1], C1[2], C1[3], C1[4], C1[5], C1[6], C1[7], h);
            bf16x8 Bhi = xposeB(C1[8], C1[9], C1[10], C1[11], C1[12], C1[13], C1[14], C1[15], h);
            vfloat16 C2 = mfma32(A2lo, Blo, b2);
            C2 = mfma32(A2hi, Bhi, C2);
            Blo = xposeB(C2[0], C2[1], C2[2], C2[3], C2[4], C2[5], C2[6], C2[7], h);
            Bhi = xposeB(C2[8], C2[9], C2[10], C2[11], C2[12], C2[13], C2[14], C2[15], h);
            vfloat16 C3 = mfma32(A3lo, Blo, zc());
            C3 = mfma32(A3hi, Bhi, C3);
            if (a0 + i != sel) {
#pragma unroll
                for (int j = 0; j < 8; ++j) sum[j] += fmaxf(C3[j] + b3s[j], 0.f);
            }
        }

        if (wave != 0) {
#pragma unroll
            for (int i = 0; i < 8; ++i) lds_red[wave - 1][i][lane] = sum[i];
        }
        __syncthreads();                       // partial sums ready

        // ---- phase 2: wave0 epilogue  ||  waves1-3 stage next tile ----
        if (wave != 0) {
            if (t + 1 < TILES_PER_BLK) {
                const float* xblk = x + (size_t)(base0 + 32) * 128;
                for (int f = tid - 64; f < 1024; f += 192) {
                    int row = f >> 5;
                    int ag  = f & 31;
                    float4 v = *(const float4*)(xblk + (size_t)f * 4);
                    int2 d;
                    d.x = pkbf(v.x, v.y);
                    d.y = pkbf(v.z, v.w);
                    *(int2*)&lds_xb[buf ^ 1][ag * XSTRIDE + row * 2] = d;
                }
            }
        } else {
#pragma unroll
            for (int j = 0; j < 3; ++j)
#pragma unroll
                for (int i = 0; i < 8; ++i) sum[i] += lds_red[j][i][lane];

            // selected-agent MLP
            bf16x8 S1   = make_afrag(sW1, sb1,     32, 32, 4,  0,  lane);
            bf16x8 S2lo = make_afrag(sW2, nullptr, 32, 32, 32, 0,  lane);
            bf16x8 S2hi = make_afrag(sW2, nullptr, 32, 32, 32, 16, lane);
            bf16x8 S3lo = make_afrag(sW3, nullptr, 16, 16, 32, 0,  lane);
            bf16x8 S3hi = make_afrag(sW3, nullptr, 16, 16, 32, 16, lane);
            vfloat16 sb2v = bvec32(sb2, lane);
            float sb3s[8];
#pragma unroll
            for (int j = 0; j < 8; ++j) sb3s[j] = sb3[(j & 3) + 8 * (j >> 2) + (h ? 4 : 0)];

            int2 dsx = *(const int2*)&lds_xb[buf][sel * XSTRIDE + c * 2];
            vfloat16 C1 = mfma32(S1, b1_from(dsx), zc());
            bf16x8 Blo = xposeB(C1[0], C1[1], C1[2], C1[3], C1[4], C1[5], C1[6], C1[7], h);
            bf16x8 Bhi = xposeB(C1[8], C1[9], C1[10], C1[11], C1[12], C1[13], C1[14], C1[15], h);
            vfloat16 C2 = mfma32(S2lo, Blo, sb2v);
            C2 = mfma32(S2hi, Bhi, C2);
            Blo = xposeB(C2[0], C2[1], C2[2], C2[3], C2[4], C2[5], C2[6], C2[7], h);
            Bhi = xposeB(C2[8], C2[9], C2[10], C2[11], C2[12], C2[13], C2[14], C2[15], h);
            vfloat16 C3s = mfma32(S3lo, Blo, zc());
            C3s = mfma32(S3hi, Bhi, C3s);

            // gate layer 1: concat([sel_out, sum_other]) @ gW1 + gb1, relu
            bf16x8 Ag_lo = make_afrag(gW1, nullptr, 32, 32, 32, 0,  lane);
            bf16x8 Ag_hi = make_afrag(gW1, nullptr, 32, 32, 32, 16, lane);
            vfloat16 gb1v = bvec32(gb1, lane);
            bf16x8 Bg_lo = xposeB(C3s[0] + sb3s[0], C3s[1] + sb3s[1],
                                  C3s[2] + sb3s[2], C3s[3] + sb3s[3],
                                  C3s[4] + sb3s[4], C3s[5] + sb3s[5],
                                  C3s[6] + sb3s[6], C3s[7] + sb3s[7], h);
            bf16x8 Bg_hi = xposeB(sum[0], sum[1], sum[2], sum[3],
                                  sum[4], sum[5], sum[6], sum[7], h);
            vfloat16 G = mfma32(Ag_lo, Bg_lo, gb1v);
            G = mfma32(Ag_hi, Bg_hi, G);
#pragma unroll
            for (int i = 0; i < 16; ++i) G[i] = fmaxf(G[i], 0.f);

            // gate layer 2 (32 -> 2) in fp32 VALU + cross-half reduce
            float q0 = 0.f, q1 = 0.f;
#pragma unroll
            for (int reg = 0; reg < 16; ++reg) {
                int row = (reg & 3) + 8 * (reg >> 2) + (h ? 4 : 0);
                q0 += G[reg] * gW2[row * 2 + 0];
                q1 += G[reg] * gW2[row * 2 + 1];
            }
            q0 += __shfl_xor(q0, 32, 64);
            q1 += __shfl_xor(q1, 32, 64);
            q0 += gb2[0];
            q1 += gb2[1];

            if (!h) {
                // action index from fp32 x (bf16 rounding near 1.0 would flip it)
                float f3 = x[(size_t)(base0 + c) * 128 + sel * 4 + 3];
                int act = (int)f3;
                act = act < 0 ? 0 : (act > 1 ? 1 : act);
                out[base0 + c] = act ? q1 : q0;
            }
        }
    }
}

extern "C" void kernel_launch(void* const* d_in, const int* in_sizes, int n_in,
                              void* d_out, int out_size, void* d_ws, size_t ws_size,
                              hipStream_t stream) {
    const float* x   = (const float*)d_in[0];
    const int*   sel = (const int*)d_in[1];
    const float* oW1 = (const float*)d_in[2];
    const float* ob1 = (const float*)d_in[3];
    const float* oW2 = (const float*)d_in[4];
    const float* ob2 = (const float*)d_in[5];
    const float* oW3 = (const float*)d_in[6];
    const float* ob3 = (const float*)d_in[7];
    const float* sW1 = (const float*)d_in[8];
    const float* sb1 = (const float*)d_in[9];
    const float* sW2 = (const float*)d_in[10];
    const float* sb2 = (const float*)d_in[11];
    const float* sW3 = (const float*)d_in[12];
    const float* sb3 = (const float*)d_in[13];
    const float* gW1 = (const float*)d_in[14];
    const float* gb1 = (const float*)d_in[15];
    const float* gW2 = (const float*)d_in[16];
    const float* gb2 = (const float*)d_in[17];
    float* out = (float*)d_out;

    const int B = in_sizes[0] / 128;                    // 65536
    const int blocks = B / (32 * TILES_PER_BLK);        // 1024 = 4 blocks/CU, all resident
    dqn_kernel<<<blocks, 256, 0, stream>>>(x, sel,
                                           oW1, ob1, oW2, ob2, oW3, ob3,
                                           sW1, sb1, sW2, sb2, sW3, sb3,
                                           gW1, gb1, gW2, gb2, out);
}

// Round 9
// 141.688 us; speedup vs baseline: 1.4801x; 1.4801x over previous
//
#include <hip/hip_runtime.h>
#include <hip/hip_bf16.h>

#define DEV __device__ __forceinline__

typedef __attribute__((ext_vector_type(8)))  __bf16    bf16x8;
typedef __attribute__((ext_vector_type(4)))  int       int4v;
typedef __attribute__((ext_vector_type(2)))  unsigned  uint2v;
typedef __attribute__((ext_vector_type(16))) float     vfloat16;

#if __has_builtin(__builtin_amdgcn_permlane32_swap)
#define HAVE_PLSWAP 1
#endif

// pack two fp32 -> one dword of two bf16, low half = first arg.
// Round-to-nearest (ties up) via +0x8000, then one v_perm_b32 byte-select.
DEV int pkbf(float a, float b) {
    unsigned ua = __builtin_bit_cast(unsigned, a) + 0x8000u;
    unsigned ub = __builtin_bit_cast(unsigned, b) + 0x8000u;
    return (int)__builtin_amdgcn_perm(ua, ub, 0x03020706u);
}

DEV bf16x8 i4_to_frag(int4v v) { return __builtin_bit_cast(bf16x8, v); }

DEV vfloat16 mfma32(bf16x8 a, bf16x8 b, vfloat16 c) {
    return __builtin_amdgcn_mfma_f32_32x32x16_bf16(a, b, c, 0, 0, 0);
}

// ---- C-layout 8-reg group -> B-frag (K=16), relu folded ----
// C layout: col=lane&31, row=(reg&3)+8*(reg>>2)+4*h   (h = lane>=32)
// B layout: n=lane&31,  k=(lane>>5)*8+j
DEV bf16x8 xposeB(float c0, float c1, float c2, float c3,
                  float c4, float c5, float c6, float c7, bool h) {
    int R0 = pkbf(fmaxf(c0, 0.f), fmaxf(c1, 0.f));   // rows (0,1)+4h
    int R1 = pkbf(fmaxf(c2, 0.f), fmaxf(c3, 0.f));   // rows (2,3)+4h
    int R2 = pkbf(fmaxf(c4, 0.f), fmaxf(c5, 0.f));   // rows (8,9)+4h
    int R3 = pkbf(fmaxf(c6, 0.f), fmaxf(c7, 0.f));   // rows (10,11)+4h
#ifdef HAVE_PLSWAP
    uint2v p0 = __builtin_amdgcn_permlane32_swap((unsigned)R0, (unsigned)R2, false, false);
    uint2v p1 = __builtin_amdgcn_permlane32_swap((unsigned)R1, (unsigned)R3, false, false);
    int4v v;
    v.x = (int)p0.x; v.y = (int)p1.x; v.z = (int)p0.y; v.w = (int)p1.y;
#else
    int S0 = h ? R0 : R2;
    int S1 = h ? R1 : R3;
    int Y0 = __shfl_xor(S0, 32, 64);
    int Y1 = __shfl_xor(S1, 32, 64);
    int4v v;
    v.x = h ? Y0 : R0;
    v.y = h ? Y1 : R1;
    v.z = h ? R2 : Y0;
    v.w = h ? R3 : Y1;
#endif
    return i4_to_frag(v);
}

// A-frag: A[m][k_global], m=lane&31, k_global = koff + 8*h + j.
// W row-major (K, ld): W[k][m].  Rows m>=Mact zero; k>=K zero.
// If bias != null, the k_global == K slot carries bias[m].
DEV bf16x8 make_afrag(const float* __restrict__ W, const float* __restrict__ bias,
                      int ld, int Mact, int K, int koff, int lane) {
    int m = lane & 31;
    int h = lane >> 5;
    int d[4];
#pragma unroll
    for (int i = 0; i < 4; ++i) {
        int k0 = koff + h * 8 + 2 * i;
        int k1 = k0 + 1;
        float w0 = 0.f, w1 = 0.f;
        if (m < Mact) {
            if (k0 < K) w0 = W[k0 * ld + m];
            else if (bias && k0 == K) w0 = bias[m];
            if (k1 < K) w1 = W[k1 * ld + m];
            else if (bias && k1 == K) w1 = bias[m];
        }
        d[i] = pkbf(w0, w1);
    }
    int4v v; v.x = d[0]; v.y = d[1]; v.z = d[2]; v.w = d[3];
    return i4_to_frag(v);
}

// bias vector in C layout (all 32 rows)
DEV vfloat16 bvec32(const float* __restrict__ b, int lane) {
    int h = lane >> 5;
    vfloat16 v;
#pragma unroll
    for (int reg = 0; reg < 16; ++reg)
        v[reg] = b[(reg & 3) + 8 * (reg >> 2) + 4 * h];
    return v;
}
// bias vector, rows 0..15 only (regs 0..7), upper 8 zero
DEV vfloat16 bvec16(const float* __restrict__ b, int lane) {
    int h = lane >> 5;
    vfloat16 v;
#pragma unroll
    for (int reg = 0; reg < 16; ++reg)
        v[reg] = (reg < 8) ? b[(reg & 3) + 8 * (reg >> 2) + 4 * h] : 0.f;
    return v;
}

DEV vfloat16 zero16() {
    vfloat16 z;
#pragma unroll
    for (int i = 0; i < 16; ++i) z[i] = 0.f;
    return z;
}

// B1 frag from pre-packed LDS dwords: x at k=0..3, 1.0 at k=4 (bias slot).
// h-lanes map to k=8..15 where A1 is zero -> no masking needed.
DEV bf16x8 b1_from(int2 d) {
    int4v v;
    v.x = d.x;
    v.y = d.y;
    v.z = 0x00003f80;          // bf16(1.0) at k=4
    v.w = 0;
    return i4_to_frag(v);
}

struct Frags {
    bf16x8 A1, A2lo, A2hi, A3lo, A3hi;
    vfloat16 b2, b3;   // L2/L3 biases as MFMA C-operand inits (L1 bias rides k=4)
};

DEV void load_frags(Frags& F,
                    const float* __restrict__ W1, const float* __restrict__ b1,
                    const float* __restrict__ W2, const float* __restrict__ b2,
                    const float* __restrict__ W3, const float* __restrict__ b3,
                    int lane) {
    F.A1   = make_afrag(W1, b1,      32, 32, 4,  0,  lane);
    F.A2lo = make_afrag(W2, nullptr, 32, 32, 32, 0,  lane);
    F.A2hi = make_afrag(W2, nullptr, 32, 32, 32, 16, lane);
    F.A3lo = make_afrag(W3, nullptr, 16, 16, 32, 0,  lane);
    F.A3hi = make_afrag(W3, nullptr, 16, 16, 32, 16, lane);
    F.b2 = bvec32(b2, lane);
    F.b3 = bvec16(b3, lane);
}

// single chain (epilogue use): L1..L3, returns pre-relu C3 (regs 0..7 valid)
DEV vfloat16 run_mlp3(bf16x8 B1, const Frags& F, bool h) {
    vfloat16 C1 = mfma32(F.A1, B1, zero16());
    bf16x8 Blo = xposeB(C1[0], C1[1], C1[2], C1[3], C1[4], C1[5], C1[6], C1[7], h);
    bf16x8 Bhi = xposeB(C1[8], C1[9], C1[10], C1[11], C1[12], C1[13], C1[14], C1[15], h);
    vfloat16 C2 = mfma32(F.A2lo, Blo, F.b2);
    C2 = mfma32(F.A2hi, Bhi, C2);
    Blo = xposeB(C2[0], C2[1], C2[2], C2[3], C2[4], C2[5], C2[6], C2[7], h);
    Bhi = xposeB(C2[8], C2[9], C2[10], C2[11], C2[12], C2[13], C2[14], C2[15], h);
    vfloat16 C3 = mfma32(F.A3lo, Blo, F.b3);
    C3 = mfma32(F.A3hi, Bhi, C3);
    return C3;
}

// LDS x-stage: pre-packed bf16, [agent][row] int2, agent stride 66 dwords
#define XSTRIDE 66

__global__ __launch_bounds__(256)
__attribute__((amdgpu_waves_per_eu(2, 2)))
// Unified (arch+AGPR) budget = 512/2 = 256 regs/wave.  The 2-chain live set
// (~180) fits entirely in ARCH VGPRs, so the compiler's MFMA pressure
// heuristic selects VGPR-form MFMA -> no v_accvgpr shuttle around every MFMA
// (R6/R7's ~22M excess VALU instrs), no scratch spill (R8's 170 MB WRITE at
// (4,4)=128 budget).  TLP 2 waves/SIMD; ILP from the 2-chain interleave.
void dqn_kernel(const float* __restrict__ x, const int* __restrict__ selp,
                const float* __restrict__ oW1, const float* __restrict__ ob1,
                const float* __restrict__ oW2, const float* __restrict__ ob2,
                const float* __restrict__ oW3, const float* __restrict__ ob3,
                const float* __restrict__ sW1, const float* __restrict__ sb1,
                const float* __restrict__ sW2, const float* __restrict__ sb2,
                const float* __restrict__ sW3, const float* __restrict__ sb3,
                const float* __restrict__ gW1, const float* __restrict__ gb1,
                const float* __restrict__ gW2, const float* __restrict__ gb2,
                float* __restrict__ out)
{
    __shared__ int   lds_xb[32 * XSTRIDE];    // 8.4 KB pre-packed bf16 x
    __shared__ float lds_red[3][8][64];       // 6 KB partial agent-sums

    const int tid  = threadIdx.x;
    const int lane = tid & 63;
    const int wave = tid >> 6;
    const bool h = lane >= 32;
    const int c = lane & 31;
    const int sel = *selp;
    const int base0 = blockIdx.x * 32;        // 32 batch rows per block

    // ---- stage x: coalesced fp32 read -> bf16 pack -> LDS [agent][row] ----
    {
        const float* xblk = x + (size_t)base0 * 128;
#pragma unroll
        for (int k = 0; k < 4; ++k) {
            int f = tid + 256 * k;            // float4 index in 32x32 tile
            int row = f >> 5;
            int ag  = f & 31;
            float4 v = *(const float4*)(xblk + (size_t)f * 4);
            int2 d;
            d.x = pkbf(v.x, v.y);
            d.y = pkbf(v.z, v.w);
            *(int2*)&lds_xb[ag * XSTRIDE + row * 2] = d;
        }
    }

    // "other"-MLP weight fragments (global; latency overlaps staging)
    Frags Fo;
    load_frags(Fo, oW1, ob1, oW2, ob2, oW3, ob3, lane);

    __syncthreads();

    // ---- main loop: 8 agents per wave, TWO chains fully interleaved ----
    float sum[8] = {0.f, 0.f, 0.f, 0.f, 0.f, 0.f, 0.f, 0.f};
    const int a0 = wave * 8;
    const int* xb = &lds_xb[a0 * XSTRIDE + c * 2];

#pragma unroll
    for (int i = 0; i < 8; i += 2) {
        int2 da = *(const int2*)(xb + i * XSTRIDE);
        int2 db = *(const int2*)(xb + (i + 1) * XSTRIDE);

        vfloat16 C1a = mfma32(Fo.A1, b1_from(da), zero16());
        vfloat16 C1b = mfma32(Fo.A1, b1_from(db), zero16());

        bf16x8 Bal = xposeB(C1a[0], C1a[1], C1a[2], C1a[3], C1a[4], C1a[5], C1a[6], C1a[7], h);
        bf16x8 Bbl = xposeB(C1b[0], C1b[1], C1b[2], C1b[3], C1b[4], C1b[5], C1b[6], C1b[7], h);
        bf16x8 Bah = xposeB(C1a[8], C1a[9], C1a[10], C1a[11], C1a[12], C1a[13], C1a[14], C1a[15], h);
        bf16x8 Bbh = xposeB(C1b[8], C1b[9], C1b[10], C1b[11], C1b[12], C1b[13], C1b[14], C1b[15], h);

        vfloat16 C2a = mfma32(Fo.A2lo, Bal, Fo.b2);
        vfloat16 C2b = mfma32(Fo.A2lo, Bbl, Fo.b2);
        C2a = mfma32(Fo.A2hi, Bah, C2a);
        C2b = mfma32(Fo.A2hi, Bbh, C2b);

        Bal = xposeB(C2a[0], C2a[1], C2a[2], C2a[3], C2a[4], C2a[5], C2a[6], C2a[7], h);
        Bbl = xposeB(C2b[0], C2b[1], C2b[2], C2b[3], C2b[4], C2b[5], C2b[6], C2b[7], h);
        Bah = xposeB(C2a[8], C2a[9], C2a[10], C2a[11], C2a[12], C2a[13], C2a[14], C2a[15], h);
        Bbh = xposeB(C2b[8], C2b[9], C2b[10], C2b[11], C2b[12], C2b[13], C2b[14], C2b[15], h);

        vfloat16 C3a = mfma32(Fo.A3lo, Bal, Fo.b3);
        vfloat16 C3b = mfma32(Fo.A3lo, Bbl, Fo.b3);
        C3a = mfma32(Fo.A3hi, Bah, C3a);
        C3b = mfma32(Fo.A3hi, Bbh, C3b);

        if (a0 + i != sel) {
#pragma unroll
            for (int j = 0; j < 8; ++j) sum[j] += fmaxf(C3a[j], 0.f);
        }
        if (a0 + i + 1 != sel) {
#pragma unroll
            for (int j = 0; j < 8; ++j) sum[j] += fmaxf(C3b[j], 0.f);
        }
    }

    // ---- merge partial sums across the 4 waves ----
    if (wave != 0) {
#pragma unroll
        for (int i = 0; i < 8; ++i) lds_red[wave - 1][i][lane] = sum[i];
    }
    __syncthreads();

    if (wave == 0) {
#pragma unroll
        for (int j = 0; j < 3; ++j)
#pragma unroll
            for (int i = 0; i < 8; ++i) sum[i] += lds_red[j][i][lane];

        // selected-agent MLP (packed x from LDS; weights from global/L2)
        Frags Fs;
        load_frags(Fs, sW1, sb1, sW2, sb2, sW3, sb3, lane);
        int2 ds = *(const int2*)&lds_xb[sel * XSTRIDE + c * 2];
        vfloat16 C3s = run_mlp3(b1_from(ds), Fs, h);

        // gate layer 1: concat([sel_out, sum_other]) @ gW1 + gb1, relu
        bf16x8 Ag_lo = make_afrag(gW1, nullptr, 32, 32, 32, 0,  lane);
        bf16x8 Ag_hi = make_afrag(gW1, nullptr, 32, 32, 32, 16, lane);
        vfloat16 gb1v = bvec32(gb1, lane);
        bf16x8 Bg_lo = xposeB(C3s[0], C3s[1], C3s[2], C3s[3],
                              C3s[4], C3s[5], C3s[6], C3s[7], h);   // relu folded
        bf16x8 Bg_hi = xposeB(sum[0], sum[1], sum[2], sum[3],
                              sum[4], sum[5], sum[6], sum[7], h);   // sums >= 0
        vfloat16 G = mfma32(Ag_lo, Bg_lo, gb1v);
        G = mfma32(Ag_hi, Bg_hi, G);
#pragma unroll
        for (int i = 0; i < 16; ++i) G[i] = fmaxf(G[i], 0.f);

        // gate layer 2 (32 -> 2) in fp32 VALU + cross-half reduce
        float q0 = 0.f, q1 = 0.f;
#pragma unroll
        for (int reg = 0; reg < 16; ++reg) {
            int row = (reg & 3) + 8 * (reg >> 2) + (h ? 4 : 0);
            q0 += G[reg] * gW2[row * 2 + 0];
            q1 += G[reg] * gW2[row * 2 + 1];
        }
        q0 += __shfl_xor(q0, 32, 64);
        q1 += __shfl_xor(q1, 32, 64);
        q0 += gb2[0];
        q1 += gb2[1];

        if (!h) {
            // action index MUST come from fp32 x (bf16 rounding of values
            // near 1.0 would flip the (int) cast)
            float f3 = x[(size_t)(base0 + c) * 128 + sel * 4 + 3];
            int act = (int)f3;
            act = act < 0 ? 0 : (act > 1 ? 1 : act);
            out[base0 + c] = act ? q1 : q0;
        }
    }
}

extern "C" void kernel_launch(void* const* d_in, const int* in_sizes, int n_in,
                              void* d_out, int out_size, void* d_ws, size_t ws_size,
                              hipStream_t stream) {
    const float* x   = (const float*)d_in[0];
    const int*   sel = (const int*)d_in[1];
    const float* oW1 = (const float*)d_in[2];
    const float* ob1 = (const float*)d_in[3];
    const float* oW2 = (const float*)d_in[4];
    const float* ob2 = (const float*)d_in[5];
    const float* oW3 = (const float*)d_in[6];
    const float* ob3 = (const float*)d_in[7];
    const float* sW1 = (const float*)d_in[8];
    const float* sb1 = (const float*)d_in[9];
    const float* sW2 = (const float*)d_in[10];
    const float* sb2 = (const float*)d_in[11];
    const float* sW3 = (const float*)d_in[12];
    const float* sb3 = (const float*)d_in[13];
    const float* gW1 = (const float*)d_in[14];
    const float* gb1 = (const float*)d_in[15];
    const float* gW2 = (const float*)d_in[16];
    const float* gb2 = (const float*)d_in[17];
    float* out = (float*)d_out;

    const int B = in_sizes[0] / 128;       // 65536
    const int blocks = B / 32;             // 32 batch rows per block, 8 agents/wave
    dqn_kernel<<<blocks, 256, 0, stream>>>(x, sel,
                                           oW1, ob1, oW2, ob2, oW3, ob3,
                                           sW1, sb1, sW2, sb2, sW3, sb3,
                                           gW1, gb1, gW2, gb2, out);
}

// Round 11
// 133.967 us; speedup vs baseline: 1.5653x; 1.0576x over previous
//
#include <hip/hip_runtime.h>
#include <hip/hip_bf16.h>

#define DEV __device__ __forceinline__

typedef __attribute__((ext_vector_type(8)))  __bf16    bf16x8;
typedef __attribute__((ext_vector_type(4)))  int       int4v;
typedef __attribute__((ext_vector_type(2)))  unsigned  uint2v;
typedef __attribute__((ext_vector_type(16))) float     vfloat16;

#if __has_builtin(__builtin_amdgcn_permlane32_swap)
#define HAVE_PLSWAP 1
#endif

// pack two fp32 -> one dword of two bf16, low half = first arg.
// Round-to-nearest (ties up) via +0x8000, then one v_perm_b32 byte-select.
DEV int pkbf(float a, float b) {
    unsigned ua = __builtin_bit_cast(unsigned, a) + 0x8000u;
    unsigned ub = __builtin_bit_cast(unsigned, b) + 0x8000u;
    return (int)__builtin_amdgcn_perm(ua, ub, 0x03020706u);
}

DEV bf16x8 i4_to_frag(int4v v) { return __builtin_bit_cast(bf16x8, v); }

// ==== MFMA forced to ARCH-VGPR form via inline asm (R6-R9: builtin lets RA
// keep accumulators in AGPRs, paying v_accvgpr shuttles around every MFMA =
// ~3x VALU inflation).  R10 lesson: asm bypasses the compiler's MAI hazard
// model, so wait-states are OUR job:
//   VALU write -> MFMA read src:            ~2-4 cyc  (lead  s_nop 3)
//   16-pass MFMA write -> VALU read dest:   ~18-24 cyc (trail s_nop 7 x3)
//   MFMA write -> MFMA read as SrcC:         0 cyc    (chained accumulate)
// Pair variants issue both interleaved chains' MFMAs back-to-back inside ONE
// asm block so chain-b's MFMA fills chain-a's hazard shadow. ====

// d1,d2 = A*{b1,b2} + 0   (inline-const srcC; results feed VALU -> trailing)
DEV void mfma2_z_t(vfloat16& d1, vfloat16& d2, bf16x8 a, bf16x8 b1, bf16x8 b2) {
    asm("s_nop 3\n\t"
        "v_mfma_f32_32x32x16_bf16 %0, %2, %3, 0\n\t"
        "v_mfma_f32_32x32x16_bf16 %1, %2, %4, 0\n\t"
        "s_nop 7\n\ts_nop 7\n\ts_nop 7"
        : "=&v"(d1), "=&v"(d2)
        : "v"(a), "v"(b1), "v"(b2));
}

// d1,d2 = A*{b1,b2} + c   (c loop-invariant; results feed chained MFMA SrcC
// next -> NO trailing nops needed)
DEV void mfma2_c_nt(vfloat16& d1, vfloat16& d2, bf16x8 a, bf16x8 b1, bf16x8 b2,
                    vfloat16 c) {
    asm("s_nop 3\n\t"
        "v_mfma_f32_32x32x16_bf16 %0, %2, %3, %5\n\t"
        "v_mfma_f32_32x32x16_bf16 %1, %2, %4, %5"
        : "=&v"(d1), "=&v"(d2)
        : "v"(a), "v"(b1), "v"(b2), "v"(c));
}

// c1 += A*b1 ; c2 += A*b2   (tied in-place D==C; results feed VALU -> trailing)
DEV void mfma2_acc_t(vfloat16& c1, vfloat16& c2, bf16x8 a, bf16x8 b1, bf16x8 b2) {
    asm("s_nop 3\n\t"
        "v_mfma_f32_32x32x16_bf16 %0, %2, %3, %0\n\t"
        "v_mfma_f32_32x32x16_bf16 %1, %2, %4, %1\n\t"
        "s_nop 7\n\ts_nop 7\n\ts_nop 7"
        : "+v"(c1), "+v"(c2)
        : "v"(a), "v"(b1), "v"(b2));
}

// single-chain variants (epilogue)
DEV vfloat16 mfma_z_t(bf16x8 a, bf16x8 b) {
    vfloat16 d;
    asm("s_nop 3\n\t"
        "v_mfma_f32_32x32x16_bf16 %0, %1, %2, 0\n\t"
        "s_nop 7\n\ts_nop 7\n\ts_nop 7"
        : "=&v"(d) : "v"(a), "v"(b));
    return d;
}
DEV vfloat16 mfma_c_nt(bf16x8 a, bf16x8 b, vfloat16 c) {
    vfloat16 d;
    asm("s_nop 3\n\t"
        "v_mfma_f32_32x32x16_bf16 %0, %1, %2, %3"
        : "=&v"(d) : "v"(a), "v"(b), "v"(c));
    return d;
}
DEV void mfma_acc_t(vfloat16& c, bf16x8 a, bf16x8 b) {
    asm("s_nop 3\n\t"
        "v_mfma_f32_32x32x16_bf16 %0, %1, %2, %0\n\t"
        "s_nop 7\n\ts_nop 7\n\ts_nop 7"
        : "+v"(c) : "v"(a), "v"(b));
}

// ---- C-layout 8-reg group -> B-frag (K=16), relu folded ----
// C layout: col=lane&31, row=(reg&3)+8*(reg>>2)+4*h   (h = lane>=32)
// B layout: n=lane&31,  k=(lane>>5)*8+j
DEV bf16x8 xposeB(float c0, float c1, float c2, float c3,
                  float c4, float c5, float c6, float c7, bool h) {
    int R0 = pkbf(fmaxf(c0, 0.f), fmaxf(c1, 0.f));   // rows (0,1)+4h
    int R1 = pkbf(fmaxf(c2, 0.f), fmaxf(c3, 0.f));   // rows (2,3)+4h
    int R2 = pkbf(fmaxf(c4, 0.f), fmaxf(c5, 0.f));   // rows (8,9)+4h
    int R3 = pkbf(fmaxf(c6, 0.f), fmaxf(c7, 0.f));   // rows (10,11)+4h
#ifdef HAVE_PLSWAP
    uint2v p0 = __builtin_amdgcn_permlane32_swap((unsigned)R0, (unsigned)R2, false, false);
    uint2v p1 = __builtin_amdgcn_permlane32_swap((unsigned)R1, (unsigned)R3, false, false);
    int4v v;
    v.x = (int)p0.x; v.y = (int)p1.x; v.z = (int)p0.y; v.w = (int)p1.y;
#else
    int S0 = h ? R0 : R2;
    int S1 = h ? R1 : R3;
    int Y0 = __shfl_xor(S0, 32, 64);
    int Y1 = __shfl_xor(S1, 32, 64);
    int4v v;
    v.x = h ? Y0 : R0;
    v.y = h ? Y1 : R1;
    v.z = h ? R2 : Y0;
    v.w = h ? R3 : Y1;
#endif
    return i4_to_frag(v);
}

// A-frag: A[m][k_global], m=lane&31, k_global = koff + 8*h + j.
// W row-major (K, ld): W[k][m].  Rows m>=Mact zero; k>=K zero.
// If bias != null, the k_global == K slot carries bias[m].
DEV bf16x8 make_afrag(const float* __restrict__ W, const float* __restrict__ bias,
                      int ld, int Mact, int K, int koff, int lane) {
    int m = lane & 31;
    int h = lane >> 5;
    int d[4];
#pragma unroll
    for (int i = 0; i < 4; ++i) {
        int k0 = koff + h * 8 + 2 * i;
        int k1 = k0 + 1;
        float w0 = 0.f, w1 = 0.f;
        if (m < Mact) {
            if (k0 < K) w0 = W[k0 * ld + m];
            else if (bias && k0 == K) w0 = bias[m];
            if (k1 < K) w1 = W[k1 * ld + m];
            else if (bias && k1 == K) w1 = bias[m];
        }
        d[i] = pkbf(w0, w1);
    }
    int4v v; v.x = d[0]; v.y = d[1]; v.z = d[2]; v.w = d[3];
    return i4_to_frag(v);
}

// bias vector in C layout (all 32 rows)
DEV vfloat16 bvec32(const float* __restrict__ b, int lane) {
    int h = lane >> 5;
    vfloat16 v;
#pragma unroll
    for (int reg = 0; reg < 16; ++reg)
        v[reg] = b[(reg & 3) + 8 * (reg >> 2) + 4 * h];
    return v;
}
// bias vector, rows 0..15 only (regs 0..7), upper 8 zero
DEV vfloat16 bvec16(const float* __restrict__ b, int lane) {
    int h = lane >> 5;
    vfloat16 v;
#pragma unroll
    for (int reg = 0; reg < 16; ++reg)
        v[reg] = (reg < 8) ? b[(reg & 3) + 8 * (reg >> 2) + 4 * h] : 0.f;
    return v;
}

// B1 frag from pre-packed LDS dwords: x at k=0..3, 1.0 at k=4 (bias slot).
// h-lanes map to k=8..15 where A1 is zero -> no masking needed.
DEV bf16x8 b1_from(int2 d) {
    int4v v;
    v.x = d.x;
    v.y = d.y;
    v.z = 0x00003f80;          // bf16(1.0) at k=4
    v.w = 0;
    return i4_to_frag(v);
}

struct Frags {
    bf16x8 A1, A2lo, A2hi, A3lo, A3hi;
    vfloat16 b2, b3;   // L2/L3 biases as MFMA C-operand inits (L1 bias rides k=4)
};

DEV void load_frags(Frags& F,
                    const float* __restrict__ W1, const float* __restrict__ b1,
                    const float* __restrict__ W2, const float* __restrict__ b2,
                    const float* __restrict__ W3, const float* __restrict__ b3,
                    int lane) {
    F.A1   = make_afrag(W1, b1,      32, 32, 4,  0,  lane);
    F.A2lo = make_afrag(W2, nullptr, 32, 32, 32, 0,  lane);
    F.A2hi = make_afrag(W2, nullptr, 32, 32, 32, 16, lane);
    F.A3lo = make_afrag(W3, nullptr, 16, 16, 32, 0,  lane);
    F.A3hi = make_afrag(W3, nullptr, 16, 16, 32, 16, lane);
    F.b2 = bvec32(b2, lane);
    F.b3 = bvec16(b3, lane);
}

// single chain (epilogue use): L1..L3, returns pre-relu C3 (regs 0..7 valid)
DEV vfloat16 run_mlp3(bf16x8 B1, const Frags& F, bool h) {
    vfloat16 C1 = mfma_z_t(F.A1, B1);
    bf16x8 Blo = xposeB(C1[0], C1[1], C1[2], C1[3], C1[4], C1[5], C1[6], C1[7], h);
    bf16x8 Bhi = xposeB(C1[8], C1[9], C1[10], C1[11], C1[12], C1[13], C1[14], C1[15], h);
    vfloat16 C2 = mfma_c_nt(F.A2lo, Blo, F.b2);
    mfma_acc_t(C2, F.A2hi, Bhi);
    Blo = xposeB(C2[0], C2[1], C2[2], C2[3], C2[4], C2[5], C2[6], C2[7], h);
    Bhi = xposeB(C2[8], C2[9], C2[10], C2[11], C2[12], C2[13], C2[14], C2[15], h);
    vfloat16 C3 = mfma_c_nt(F.A3lo, Blo, F.b3);
    mfma_acc_t(C3, F.A3hi, Bhi);
    return C3;
}

// LDS x-stage: pre-packed bf16, [agent][row] int2, agent stride 66 dwords
#define XSTRIDE 66

__global__ __launch_bounds__(256)
void dqn_kernel(const float* __restrict__ x, const int* __restrict__ selp,
                const float* __restrict__ oW1, const float* __restrict__ ob1,
                const float* __restrict__ oW2, const float* __restrict__ ob2,
                const float* __restrict__ oW3, const float* __restrict__ ob3,
                const float* __restrict__ sW1, const float* __restrict__ sb1,
                const float* __restrict__ sW2, const float* __restrict__ sb2,
                const float* __restrict__ sW3, const float* __restrict__ sb3,
                const float* __restrict__ gW1, const float* __restrict__ gb1,
                const float* __restrict__ gW2, const float* __restrict__ gb2,
                float* __restrict__ out)
{
    __shared__ int   lds_xb[32 * XSTRIDE];    // 8.4 KB pre-packed bf16 x
    __shared__ float lds_red[3][8][64];       // 6 KB partial agent-sums

    const int tid  = threadIdx.x;
    const int lane = tid & 63;
    const int wave = tid >> 6;
    const bool h = lane >= 32;
    const int c = lane & 31;
    const int sel = *selp;
    const int base0 = blockIdx.x * 32;        // 32 batch rows per block

    // ---- stage x: coalesced fp32 read -> bf16 pack -> LDS [agent][row] ----
    {
        const float* xblk = x + (size_t)base0 * 128;
#pragma unroll
        for (int k = 0; k < 4; ++k) {
            int f = tid + 256 * k;            // float4 index in 32x32 tile
            int row = f >> 5;
            int ag  = f & 31;
            float4 v = *(const float4*)(xblk + (size_t)f * 4);
            int2 d;
            d.x = pkbf(v.x, v.y);
            d.y = pkbf(v.z, v.w);
            *(int2*)&lds_xb[ag * XSTRIDE + row * 2] = d;
        }
    }

    // "other"-MLP weight fragments (global; latency overlaps staging)
    Frags Fo;
    load_frags(Fo, oW1, ob1, oW2, ob2, oW3, ob3, lane);

    __syncthreads();

    // ---- main loop: 8 agents per wave, TWO chains interleaved (paired asm) ----
    float sum[8] = {0.f, 0.f, 0.f, 0.f, 0.f, 0.f, 0.f, 0.f};
    const int a0 = wave * 8;
    const int* xb = &lds_xb[a0 * XSTRIDE + c * 2];

#pragma unroll
    for (int i = 0; i < 8; i += 2) {
        int2 da = *(const int2*)(xb + i * XSTRIDE);
        int2 db = *(const int2*)(xb + (i + 1) * XSTRIDE);

        vfloat16 C1a, C1b;
        mfma2_z_t(C1a, C1b, Fo.A1, b1_from(da), b1_from(db));

        bf16x8 Bal = xposeB(C1a[0], C1a[1], C1a[2], C1a[3], C1a[4], C1a[5], C1a[6], C1a[7], h);
        bf16x8 Bbl = xposeB(C1b[0], C1b[1], C1b[2], C1b[3], C1b[4], C1b[5], C1b[6], C1b[7], h);
        bf16x8 Bah = xposeB(C1a[8], C1a[9], C1a[10], C1a[11], C1a[12], C1a[13], C1a[14], C1a[15], h);
        bf16x8 Bbh = xposeB(C1b[8], C1b[9], C1b[10], C1b[11], C1b[12], C1b[13], C1b[14], C1b[15], h);

        vfloat16 C2a, C2b;
        mfma2_c_nt(C2a, C2b, Fo.A2lo, Bal, Bbl, Fo.b2);
        mfma2_acc_t(C2a, C2b, Fo.A2hi, Bah, Bbh);

        Bal = xposeB(C2a[0], C2a[1], C2a[2], C2a[3], C2a[4], C2a[5], C2a[6], C2a[7], h);
        Bbl = xposeB(C2b[0], C2b[1], C2b[2], C2b[3], C2b[4], C2b[5], C2b[6], C2b[7], h);
        Bah = xposeB(C2a[8], C2a[9], C2a[10], C2a[11], C2a[12], C2a[13], C2a[14], C2a[15], h);
        Bbh = xposeB(C2b[8], C2b[9], C2b[10], C2b[11], C2b[12], C2b[13], C2b[14], C2b[15], h);

        vfloat16 C3a, C3b;
        mfma2_c_nt(C3a, C3b, Fo.A3lo, Bal, Bbl, Fo.b3);
        mfma2_acc_t(C3a, C3b, Fo.A3hi, Bah, Bbh);

        if (a0 + i != sel) {
#pragma unroll
            for (int j = 0; j < 8; ++j) sum[j] += fmaxf(C3a[j], 0.f);
        }
        if (a0 + i + 1 != sel) {
#pragma unroll
            for (int j = 0; j < 8; ++j) sum[j] += fmaxf(C3b[j], 0.f);
        }
    }

    // ---- merge partial sums across the 4 waves ----
    if (wave != 0) {
#pragma unroll
        for (int i = 0; i < 8; ++i) lds_red[wave - 1][i][lane] = sum[i];
    }
    __syncthreads();

    if (wave == 0) {
#pragma unroll
        for (int j = 0; j < 3; ++j)
#pragma unroll
            for (int i = 0; i < 8; ++i) sum[i] += lds_red[j][i][lane];

        // selected-agent MLP (packed x from LDS; weights from global/L2)
        Frags Fs;
        load_frags(Fs, sW1, sb1, sW2, sb2, sW3, sb3, lane);
        int2 ds = *(const int2*)&lds_xb[sel * XSTRIDE + c * 2];
        vfloat16 C3s = run_mlp3(b1_from(ds), Fs, h);

        // gate layer 1: concat([sel_out, sum_other]) @ gW1 + gb1, relu
        bf16x8 Ag_lo = make_afrag(gW1, nullptr, 32, 32, 32, 0,  lane);
        bf16x8 Ag_hi = make_afrag(gW1, nullptr, 32, 32, 32, 16, lane);
        vfloat16 gb1v = bvec32(gb1, lane);
        bf16x8 Bg_lo = xposeB(C3s[0], C3s[1], C3s[2], C3s[3],
                              C3s[4], C3s[5], C3s[6], C3s[7], h);   // relu folded
        bf16x8 Bg_hi = xposeB(sum[0], sum[1], sum[2], sum[3],
                              sum[4], sum[5], sum[6], sum[7], h);   // sums >= 0
        vfloat16 G = mfma_c_nt(Ag_lo, Bg_lo, gb1v);
        mfma_acc_t(G, Ag_hi, Bg_hi);
#pragma unroll
        for (int i = 0; i < 16; ++i) G[i] = fmaxf(G[i], 0.f);

        // gate layer 2 (32 -> 2) in fp32 VALU + cross-half reduce
        float q0 = 0.f, q1 = 0.f;
#pragma unroll
        for (int reg = 0; reg < 16; ++reg) {
            int row = (reg & 3) + 8 * (reg >> 2) + (h ? 4 : 0);
            q0 += G[reg] * gW2[row * 2 + 0];
            q1 += G[reg] * gW2[row * 2 + 1];
        }
        q0 += __shfl_xor(q0, 32, 64);
        q1 += __shfl_xor(q1, 32, 64);
        q0 += gb2[0];
        q1 += gb2[1];

        if (!h) {
            // action index MUST come from fp32 x (bf16 rounding of values
            // near 1.0 would flip the (int) cast)
            float f3 = x[(size_t)(base0 + c) * 128 + sel * 4 + 3];
            int act = (int)f3;
            act = act < 0 ? 0 : (act > 1 ? 1 : act);
            out[base0 + c] = act ? q1 : q0;
        }
    }
}

extern "C" void kernel_launch(void* const* d_in, const int* in_sizes, int n_in,
                              void* d_out, int out_size, void* d_ws, size_t ws_size,
                              hipStream_t stream) {
    const float* x   = (const float*)d_in[0];
    const int*   sel = (const int*)d_in[1];
    const float* oW1 = (const float*)d_in[2];
    const float* ob1 = (const float*)d_in[3];
    const float* oW2 = (const float*)d_in[4];
    const float* ob2 = (const float*)d_in[5];
    const float* oW3 = (const float*)d_in[6];
    const float* ob3 = (const float*)d_in[7];
    const float* sW1 = (const float*)d_in[8];
    const float* sb1 = (const float*)d_in[9];
    const float* sW2 = (const float*)d_in[10];
    const float* sb2 = (const float*)d_in[11];
    const float* sW3 = (const float*)d_in[12];
    const float* sb3 = (const float*)d_in[13];
    const float* gW1 = (const float*)d_in[14];
    const float* gb1 = (const float*)d_in[15];
    const float* gW2 = (const float*)d_in[16];
    const float* gb2 = (const float*)d_in[17];
    float* out = (float*)d_out;

    const int B = in_sizes[0] / 128;       // 65536
    const int blocks = B / 32;             // 32 batch rows per block, 8 agents/wave
    dqn_kernel<<<blocks, 256, 0, stream>>>(x, sel,
                                           oW1, ob1, oW2, ob2, oW3, ob3,
                                           sW1, sb1, sW2, sb2, sW3, sb3,
                                           gW1, gb1, gW2, gb2, out);
}